// Round 5
// baseline (167.982 us; speedup 1.0000x reference)
//
#include <hip/hip_runtime.h>

typedef _Float16 f16;
typedef _Float16 f16x8 __attribute__((ext_vector_type(8)));
typedef _Float16 f16x4 __attribute__((ext_vector_type(4)));
typedef float f32x4 __attribute__((ext_vector_type(4)));
typedef float f32x16 __attribute__((ext_vector_type(16)));

#define GDIM 52
#define GG 2704          // 52*52
#define CIN 256
#define CMID 512
#define COUT 75
#define NIMG 16
#define SPT 192          // conv1 spatial tile
#define NSPB 15          // ceil(2704/192)
#define PH 60            // padded rows in x16p
#define PW 54            // padded cols

// LDS map (bytes): At[3] @ 0 (3 x 16384), slab[2] @ 49152 (2 x 32768) = 114688
#define AT_OFF 0
#define AT_SZ 16384
#define SLAB_OFF 49152
#define SLAB_SZ 32768

#define VMCNT(n) asm volatile("s_waitcnt vmcnt(" #n ")" ::: "memory")

__device__ __forceinline__ float sigmoidf_(float x) {
    return 1.0f / (1.0f + __expf(-x));
}

__device__ __forceinline__ void gload16(const void* g, void* l) {
    __builtin_amdgcn_global_load_lds(
        (const __attribute__((address_space(1))) unsigned int*)g,
        (__attribute__((address_space(3))) unsigned int*)l, 16, 0, 0);
}

// ---- zero the pad borders of x16p (rows 0,53..59; cols 0,53) ----
__global__ __launch_bounds__(256) void k_zero_border(f16* __restrict__ x16p) {
    int ic = blockIdx.x;             // img*8 + ck
    int tid = threadIdx.x;
    f16x8 z;
#pragma unroll
    for (int k = 0; k < 8; ++k) z[k] = (f16)0;
    for (int j = tid; j < 536; j += 256) {
        int row, col;
        if (j < 432) { int r = j / 54; row = (r == 0) ? 0 : 52 + r; col = j % 54; }
        else { int k = j - 432; row = 1 + (k >> 1); col = (k & 1) * 53; }
        f16* p = x16p + (((size_t)ic * PH + row) * PW + col) * 32;
#pragma unroll
        for (int q = 0; q < 4; ++q) *(f16x8*)(p + q * 8) = z;
    }
}

// ---- prep: x [img][ci][hw] f32 -> x16p [img][ck][h+1][w+1][32ci] f16 (padded) ----
__global__ __launch_bounds__(256) void k_prep_x(const float* __restrict__ x,
                                                f16* __restrict__ x16p) {
    __shared__ float ls[32][133];
    int hw0 = blockIdx.x * 128, ck = blockIdx.y, img = blockIdx.z;
    int tid = threadIdx.x;
    const float* xb = x + ((size_t)img * CIN + ck * 32) * GG;
#pragma unroll
    for (int i = 0; i < 16; ++i) {
        int idx = tid + i * 256;
        int r = idx >> 7, c = idx & 127;
        int hw = hw0 + c;
        ls[r][c] = (hw < GG) ? xb[(size_t)r * GG + hw] : 0.0f;
    }
    __syncthreads();
    int col = tid >> 1, half = tid & 1;
    int hw = hw0 + col;
    if (hw < GG) {
        int h = hw / GDIM, w = hw % GDIM;
        f16* dst = x16p + ((((size_t)img * 8 + ck) * PH + h + 1) * PW + (w + 1)) * 32 + half * 16;
        f16x8 o0, o1;
#pragma unroll
        for (int j = 0; j < 8; ++j) o0[j] = (f16)ls[half * 16 + j][col];
#pragma unroll
        for (int j = 0; j < 8; ++j) o1[j] = (f16)ls[half * 16 + 8 + j][col];
        *(f16x8*)dst = o0;
        *(f16x8*)(dst + 8) = o1;
    }
}

// ---- prep: weights + BN fold.  w16 layout [tap][ck][co][32ci] ----
__global__ __launch_bounds__(256) void k_prep_w(
    const float* __restrict__ w1, const float* __restrict__ w2,
    const float* __restrict__ gamma, const float* __restrict__ beta,
    const float* __restrict__ mean, const float* __restrict__ var,
    f16* __restrict__ w16, f16* __restrict__ w2_16,
    float* __restrict__ bnscale, float* __restrict__ bnshift) {
    int i = blockIdx.x * 256 + threadIdx.x;   // exactly 9*8*512*32 = 1,179,648 threads
    int cl = i & 31;
    int co = (i >> 5) & 511;
    int ckt = i >> 14;          // tap*8 + ck
    int ck = ckt & 7, tap = ckt >> 3;
    int ci = ck * 32 + cl;
    w16[i] = (f16)w1[(size_t)co * 2304 + ci * 9 + tap];
    if (i < COUT * CMID) w2_16[i] = (f16)w2[i];
    if (i < CMID) {
        float s = gamma[i] * rsqrtf(var[i] + 1e-5f);
        bnscale[i] = s;
        bnshift[i] = beta[i] - mean[i] * s;
    }
}

// ---- conv1: 3x3 + BN + LeakyReLU -> y16 [half][img][n][256co] ----
// 256 thr / 4 waves (2 wm x 2 wn); block 256co x 192sp; wave 128co x 96sp.
// 32x32x16 MFMA. 2-deep A prefetch (3 bufs), slab 2 bufs, frag double-buffer:
// at tap t: issue DMA A(t+2); vmcnt; barrier; ds_read frags(t+1); MFMA(t).
__global__ __launch_bounds__(256, 1) void k_conv1(
    const f16* __restrict__ x16p, const f16* __restrict__ w16,
    const float* __restrict__ bnscale, const float* __restrict__ bnshift,
    f16* __restrict__ y16) {
    __shared__ __align__(16) char smem[114688];
    int img = blockIdx.x / NSPB, sb = blockIdx.x % NSPB;
    int n0 = sb * SPT;
    int h_lo = n0 / GDIM;
    int half = blockIdx.y;
    int co0 = half * 256;
    int tid = threadIdx.x;
    int lane = tid & 63, wave = tid >> 6;
    int wm = wave >> 1, wn = wave & 1;
    int l31 = lane & 31, hi = lane >> 5;

    int roff[3];   // pixel byte-offset/2 (f16 units) in slab
#pragma unroll
    for (int nt = 0; nt < 3; ++nt) {
        int n = n0 + wn * 96 + nt * 32 + l31;
        int nc = n < GG ? n : GG - 1;
        int hh = nc / GDIM, ww = nc % GDIM;
        roff[nt] = ((hh - h_lo + 1) * PW + (ww + 1)) * 8;
    }

    f32x16 acc[4][3];
#pragma unroll
    for (int a = 0; a < 4; ++a)
#pragma unroll
        for (int b = 0; b < 3; ++b)
#pragma unroll
            for (int i = 0; i < 16; ++i) acc[a][b][i] = 0.f;

    const f16* xbase = x16p + ((size_t)img * 8 * PH + h_lo) * (PW * 32);
    f16x8 fa[2][8], fb[2][6];

    // ---- prologue: stage A(0), slab(0), A(1); wait; read frags(0) ----
    {
        const f16* wA = w16 + (size_t)co0 * 32;   // tap0 ck0
        f16* dst = (f16*)(smem + AT_OFF);
#pragma unroll
        for (int p = 0; p < 4; ++p) {
            int cix = p * 256 + tid;
            gload16(wA + (size_t)(cix & 255) * 32 + (cix >> 8) * 8, dst + (size_t)cix * 8);
        }
        f16* sd = (f16*)(smem + SLAB_OFF);
#pragma unroll
        for (int p = 0; p < 8; ++p) {
            int cix = p * 256 + tid;
            int pix = cix & 511; if (pix > 377) pix = 377;
            gload16(xbase + (size_t)pix * 32 + (cix >> 9) * 8, sd + (size_t)cix * 8);
        }
        const f16* wA1 = w16 + ((size_t)(1 * 8 + 0) * 512 + co0) * 32;  // tap1 ck0
        f16* dst1 = (f16*)(smem + AT_OFF + AT_SZ);
#pragma unroll
        for (int p = 0; p < 4; ++p) {
            int cix = p * 256 + tid;
            gload16(wA1 + (size_t)(cix & 255) * 32 + (cix >> 8) * 8, dst1 + (size_t)cix * 8);
        }
    }
    VMCNT(4);
    __builtin_amdgcn_s_barrier();
    __builtin_amdgcn_sched_barrier(0);
    {   // frags(0): A from buf0, B from slab0, tap 0
        const f16* Ab = (const f16*)(smem + AT_OFF);
        const f16* Sb = (const f16*)(smem + SLAB_OFF);
        const int tappix = -PW - 1;
#pragma unroll
        for (int mt = 0; mt < 4; ++mt)
#pragma unroll
            for (int kh = 0; kh < 2; ++kh)
                fa[0][mt * 2 + kh] = *(const f16x8*)(Ab + (kh * 2 + hi) * 2048 +
                                                    (wm * 128 + mt * 32 + l31) * 8);
#pragma unroll
        for (int nt = 0; nt < 3; ++nt)
#pragma unroll
            for (int kh = 0; kh < 2; ++kh)
                fb[0][nt * 2 + kh] = *(const f16x8*)(Sb + (kh * 2 + hi) * 4096 +
                                                    roff[nt] + tappix * 8);
    }
    __builtin_amdgcn_sched_barrier(0);

    for (int ck2 = 0; ck2 < 4; ++ck2) {
#pragma unroll
        for (int u = 0; u < 18; ++u) {     // t = ck2*18 + u ; tap = u%9
            // ---- c: issue DMA A(t+2) (clamped dummy at tail) ----
            {
                const int tapn = (u + 2) % 9;
                int ckn = 2 * ck2 + (u + 2) / 9; if (ckn > 7) ckn = 7;
                const f16* wA = w16 + ((size_t)(tapn * 8 + ckn) * 512 + co0) * 32;
                f16* dst = (f16*)(smem + AT_OFF + ((u + 2) % 3) * AT_SZ);
#pragma unroll
                for (int p = 0; p < 4; ++p) {
                    int cix = p * 256 + tid;
                    gload16(wA + (size_t)(cix & 255) * 32 + (cix >> 8) * 8,
                            dst + (size_t)cix * 8);
                }
            }
            if (u == 1 || u == 10) {   // slab(ck+1) (clamped at last ck)
                const int sbuf = (u / 9 + 1) & 1;
                int ckn = 2 * ck2 + u / 9 + 1; if (ckn > 7) ckn = 7;
                const f16* sg = xbase + (size_t)ckn * (PH * PW * 32);
                f16* sd = (f16*)(smem + SLAB_OFF + sbuf * SLAB_SZ);
#pragma unroll
                for (int p = 0; p < 8; ++p) {
                    int cix = p * 256 + tid;
                    int pix = cix & 511; if (pix > 377) pix = 377;
                    gload16(sg + (size_t)pix * 32 + (cix >> 9) * 8, sd + (size_t)cix * 8);
                }
            }
            // ---- counted wait + rendezvous ----
            if (u == 1 || u == 2 || u == 10 || u == 11) VMCNT(12); else VMCNT(4);
            __builtin_amdgcn_s_barrier();
            __builtin_amdgcn_sched_barrier(0);
            // ---- e: ds_read frags(t+1) into set[(u+1)&1] ----
            if (!(u == 17 && ck2 == 3)) {
                const int un = u + 1;
                const f16* Ab = (const f16*)(smem + AT_OFF + (un % 3) * AT_SZ);
                const f16* Sb = (const f16*)(smem + SLAB_OFF + ((un / 9) & 1) * SLAB_SZ);
                const int tapn = un % 9;
                const int tappix = (tapn / 3 - 1) * PW + (tapn % 3 - 1);
#pragma unroll
                for (int mt = 0; mt < 4; ++mt)
#pragma unroll
                    for (int kh = 0; kh < 2; ++kh)
                        fa[un & 1][mt * 2 + kh] =
                            *(const f16x8*)(Ab + (kh * 2 + hi) * 2048 +
                                            (wm * 128 + mt * 32 + l31) * 8);
#pragma unroll
                for (int nt = 0; nt < 3; ++nt)
#pragma unroll
                    for (int kh = 0; kh < 2; ++kh)
                        fb[un & 1][nt * 2 + kh] =
                            *(const f16x8*)(Sb + (kh * 2 + hi) * 4096 +
                                            roff[nt] + tappix * 8);
            }
            __builtin_amdgcn_sched_barrier(0);
            // ---- g: MFMA(t) from set[u&1] ----
#pragma unroll
            for (int kh = 0; kh < 2; ++kh)
#pragma unroll
                for (int nt = 0; nt < 3; ++nt)
#pragma unroll
                    for (int mt = 0; mt < 4; ++mt)
                        acc[mt][nt] = __builtin_amdgcn_mfma_f32_32x32x16_f16(
                            fa[u & 1][mt * 2 + kh], fb[u & 1][nt * 2 + kh],
                            acc[mt][nt], 0, 0, 0);
            __builtin_amdgcn_sched_barrier(0);
        }
    }
    // ---- epilogue: drain DMAs, BN + leaky -> tb (stride 264) -> linear y16 ----
    VMCNT(0);
    __syncthreads();
    f16* tb = (f16*)smem;
#pragma unroll
    for (int mt = 0; mt < 4; ++mt)
#pragma unroll
        for (int q = 0; q < 4; ++q) {
            int co_l = wm * 128 + mt * 32 + q * 8 + hi * 4;
            f32x4 sc = *(const f32x4*)(bnscale + co0 + co_l);
            f32x4 sh = *(const f32x4*)(bnshift + co0 + co_l);
#pragma unroll
            for (int nt = 0; nt < 3; ++nt) {
                int pix_l = wn * 96 + nt * 32 + l31;
                f16x4 o;
#pragma unroll
                for (int i = 0; i < 4; ++i) {
                    float v = acc[mt][nt][q * 4 + i] * sc[i] + sh[i];
                    o[i] = (f16)(v > 0.f ? v : 0.1f * v);
                }
                *(f16x4*)(tb + pix_l * 264 + co_l) = o;
            }
        }
    __syncthreads();
    int valid = GG - n0; if (valid > SPT) valid = SPT;
    f16* yb = y16 + (size_t)half * (NIMG * (size_t)GG * 256) + ((size_t)img * GG + n0) * 256;
#pragma unroll
    for (int p = 0; p < 24; ++p) {
        int u = p * 256 + tid, pl = u >> 5, slot = u & 31;
        if (pl < valid)
            *(f16x8*)(yb + (size_t)pl * 256 + slot * 8) =
                *(const f16x8*)(tb + pl * 264 + slot * 8);
    }
}

// ---- conv2 (1x1, K=512) + bias + YOLO decode. 256 thr / 4 waves, 128 n per block ----
__global__ __launch_bounds__(256) void k_conv2(
    const f16* __restrict__ y16, const f16* __restrict__ w2_16,
    const float* __restrict__ b2, float* __restrict__ out) {
    __shared__ float ct[128][81];   // 41472 B
    int img = blockIdx.x / 22, nb = blockIdx.x % 22;
    int n0 = nb * 128;
    int tid = threadIdx.x;
    int lane = tid & 63, wave = tid >> 6;
    int l15 = lane & 15, kg = lane >> 4;

    f32x4 acc[5][2];
#pragma unroll
    for (int a = 0; a < 5; ++a)
#pragma unroll
        for (int b = 0; b < 2; ++b) {
            acc[a][b][0] = 0.f; acc[a][b][1] = 0.f;
            acc[a][b][2] = 0.f; acc[a][b][3] = 0.f;
        }

    int nn[2];
#pragma unroll
    for (int nf = 0; nf < 2; ++nf) {
        int n = n0 + wave * 32 + nf * 16 + l15;
        nn[nf] = n < GG ? n : GG - 1;
    }
    for (int c0 = 0; c0 < CMID; c0 += 32) {
        const f16* yb = y16 + (size_t)(c0 >> 8) * (NIMG * (size_t)GG * 256) +
                        (size_t)img * GG * 256;
        int c = c0 & 255;
        f16x8 af[5];
#pragma unroll
        for (int mf = 0; mf < 5; ++mf) {
            int co = mf * 16 + l15;
            if (co < COUT)
                af[mf] = *(const f16x8*)(w2_16 + (size_t)co * CMID + c0 + kg * 8);
            else {
#pragma unroll
                for (int k = 0; k < 8; ++k) af[mf][k] = (f16)0;
            }
        }
#pragma unroll
        for (int nf = 0; nf < 2; ++nf) {
            f16x8 bf = *(const f16x8*)(yb + (size_t)nn[nf] * 256 + c + kg * 8);
#pragma unroll
            for (int mf = 0; mf < 5; ++mf)
                acc[mf][nf] = __builtin_amdgcn_mfma_f32_16x16x32_f16(
                    af[mf], bf, acc[mf][nf], 0, 0, 0);
        }
    }
#pragma unroll
    for (int mf = 0; mf < 5; ++mf)
#pragma unroll
        for (int nf = 0; nf < 2; ++nf)
            *(f32x4*)(&ct[wave * 32 + nf * 16 + l15][mf * 16 + kg * 4]) = acc[mf][nf];
    __syncthreads();
    // decode: 384 (anchor, n) items over 256 threads
    for (int j = tid; j < 384; j += 256) {
        int a = j >> 7, nl = j & 127;
        int n = n0 + nl;
        if (n >= GG) continue;
        const float* t = &ct[nl][a * 25];
        float tv[25];
#pragma unroll
        for (int q = 0; q < 25; ++q) tv[q] = t[q] + b2[a * 25 + q];
        int h = n / GDIM, w = n % GDIM;
        const float AW[3] = {10.f, 16.f, 33.f};
        const float AH[3] = {13.f, 30.f, 23.f};
        float bx = (sigmoidf_(tv[0]) + (float)w) * 8.0f;
        float by = (sigmoidf_(tv[1]) + (float)h) * 8.0f;
        float bw_ = __expf(tv[2]) * AW[a];
        float bh_ = __expf(tv[3]) * AH[a];
        float* o = out + ((size_t)img * 8112 + (size_t)a * GG + n) * 25;
        o[0] = bx; o[1] = by; o[2] = bw_; o[3] = bh_;
        o[4] = sigmoidf_(tv[4]);
#pragma unroll
        for (int q = 0; q < 20; ++q) o[5 + q] = sigmoidf_(tv[5 + q]);
    }
}

extern "C" void kernel_launch(void* const* d_in, const int* in_sizes, int n_in,
                              void* d_out, int out_size, void* d_ws, size_t ws_size,
                              hipStream_t stream) {
    (void)in_sizes; (void)n_in; (void)out_size; (void)ws_size;
    const float* x     = (const float*)d_in[0];
    const float* w1    = (const float*)d_in[1];
    const float* gamma = (const float*)d_in[2];
    const float* beta  = (const float*)d_in[3];
    const float* mean  = (const float*)d_in[4];
    const float* var   = (const float*)d_in[5];
    const float* w2    = (const float*)d_in[6];
    const float* b2    = (const float*)d_in[7];
    float* out = (float*)d_out;

    char* ws = (char*)d_ws;
    // x16p: 16*8*60*54*32*2 = 26,542,080 B
    f16* x16p     = (f16*)(ws);
    f16* w16      = (f16*)(ws + 26542080);     // 2,359,296 B
    f16* w2_16    = (f16*)(ws + 28901376);     //    76,800 B
    float* bnscale = (float*)(ws + 28978176);  //     2,048 B
    float* bnshift = (float*)(ws + 28980224);  //     2,048 B
    f16* y16      = (f16*)(ws + 28982272);     // 44,302,336 B (total ~73.3 MB)

    k_zero_border<<<NIMG * 8, 256, 0, stream>>>(x16p);
    k_prep_x<<<dim3(22, 8, NIMG), 256, 0, stream>>>(x, x16p);
    k_prep_w<<<4608, 256, 0, stream>>>(w1, w2, gamma, beta, mean, var,
                                       w16, w2_16, bnscale, bnshift);
    k_conv1<<<dim3(NIMG * NSPB, 2), 256, 0, stream>>>(x16p, w16, bnscale,
                                                      bnshift, y16);
    k_conv2<<<NIMG * 22, 256, 0, stream>>>(y16, w2_16, b2, out);
}

// Round 6
// 167.624 us; speedup vs baseline: 1.0021x; 1.0021x over previous
//
#include <hip/hip_runtime.h>

typedef _Float16 f16;
typedef _Float16 f16x8 __attribute__((ext_vector_type(8)));
typedef _Float16 f16x4 __attribute__((ext_vector_type(4)));
typedef float f32x4 __attribute__((ext_vector_type(4)));

#define GDIM 52
#define GG 2704          // 52*52
#define CIN 256
#define CMID 512
#define COUT 75
#define NIMG 16
#define SPT 192          // conv1 spatial tile
#define NSPB 15          // ceil(2704/192)
#define PH 60            // padded rows in x16p
#define PW 54            // padded cols

// LDS map (bytes): At[4] @ 0 (4 x 16384 = 64 KB), slab[2] @ 65536 (2 x 32768) -> 128 KB
#define AT_OFF 0
#define AT_SZ 16384
#define SLAB_OFF 65536
#define SLAB_SZ 32768

#define VMCNT(n) asm volatile("s_waitcnt vmcnt(" #n ")" ::: "memory")

__device__ __forceinline__ float sigmoidf_(float x) {
    return 1.0f / (1.0f + __expf(-x));
}

__device__ __forceinline__ void gload16(const void* g, void* l) {
    __builtin_amdgcn_global_load_lds(
        (const __attribute__((address_space(1))) unsigned int*)g,
        (__attribute__((address_space(3))) unsigned int*)l, 16, 0, 0);
}

// ---- zero the pad borders of x16p (rows 0,53..59; cols 0,53) ----
__global__ __launch_bounds__(256) void k_zero_border(f16* __restrict__ x16p) {
    int ic = blockIdx.x;             // img*8 + ck
    int tid = threadIdx.x;
    f16x8 z;
#pragma unroll
    for (int k = 0; k < 8; ++k) z[k] = (f16)0;
    for (int j = tid; j < 536; j += 256) {
        int row, col;
        if (j < 432) { int r = j / 54; row = (r == 0) ? 0 : 52 + r; col = j % 54; }
        else { int k = j - 432; row = 1 + (k >> 1); col = (k & 1) * 53; }
        f16* p = x16p + (((size_t)ic * PH + row) * PW + col) * 32;
#pragma unroll
        for (int q = 0; q < 4; ++q) *(f16x8*)(p + q * 8) = z;
    }
}

// ---- prep: x [img][ci][hw] f32 -> x16p [img][ck][h+1][w+1][32ci] f16 (padded) ----
__global__ __launch_bounds__(256) void k_prep_x(const float* __restrict__ x,
                                                f16* __restrict__ x16p) {
    __shared__ float ls[32][133];
    int hw0 = blockIdx.x * 128, ck = blockIdx.y, img = blockIdx.z;
    int tid = threadIdx.x;
    const float* xb = x + ((size_t)img * CIN + ck * 32) * GG;
#pragma unroll
    for (int i = 0; i < 16; ++i) {
        int idx = tid + i * 256;
        int r = idx >> 7, c = idx & 127;
        int hw = hw0 + c;
        ls[r][c] = (hw < GG) ? xb[(size_t)r * GG + hw] : 0.0f;
    }
    __syncthreads();
    int col = tid >> 1, half = tid & 1;
    int hw = hw0 + col;
    if (hw < GG) {
        int h = hw / GDIM, w = hw % GDIM;
        f16* dst = x16p + ((((size_t)img * 8 + ck) * PH + h + 1) * PW + (w + 1)) * 32 + half * 16;
        f16x8 o0, o1;
#pragma unroll
        for (int j = 0; j < 8; ++j) o0[j] = (f16)ls[half * 16 + j][col];
#pragma unroll
        for (int j = 0; j < 8; ++j) o1[j] = (f16)ls[half * 16 + 8 + j][col];
        *(f16x8*)dst = o0;
        *(f16x8*)(dst + 8) = o1;
    }
}

// ---- prep: weights + BN fold.  w16 layout [tap][ck][co][32ci] ----
__global__ __launch_bounds__(256) void k_prep_w(
    const float* __restrict__ w1, const float* __restrict__ w2,
    const float* __restrict__ gamma, const float* __restrict__ beta,
    const float* __restrict__ mean, const float* __restrict__ var,
    f16* __restrict__ w16, f16* __restrict__ w2_16,
    float* __restrict__ bnscale, float* __restrict__ bnshift) {
    int i = blockIdx.x * 256 + threadIdx.x;   // exactly 9*8*512*32 = 1,179,648 threads
    int cl = i & 31;
    int co = (i >> 5) & 511;
    int ckt = i >> 14;          // tap*8 + ck
    int ck = ckt & 7, tap = ckt >> 3;
    int ci = ck * 32 + cl;
    w16[i] = (f16)w1[(size_t)co * 2304 + ci * 9 + tap];
    if (i < COUT * CMID) w2_16[i] = (f16)w2[i];
    if (i < CMID) {
        float s = gamma[i] * rsqrtf(var[i] + 1e-5f);
        bnscale[i] = s;
        bnshift[i] = beta[i] - mean[i] * s;
    }
}

// ---- conv1: 3x3 + BN + LeakyReLU -> y16 [half][img][n][256co] ----
// 512 thr / 8 waves (4 wm x 2 wn); block 256co x 192sp; wave 64co x 96sp.
// 16x16x32 MFMA. Frag double-buffer: at iter t issue DMA A(t+2) (4 A-bufs),
// counted vmcnt, barrier, ds_read frags(t+1), MFMA(t). Slab 2 bufs staged at
// t%9==1 (out-of-range stage redirected into the dead A-buffer).
__global__ __launch_bounds__(512, 2) void k_conv1(
    const f16* __restrict__ x16p, const f16* __restrict__ w16,
    const float* __restrict__ bnscale, const float* __restrict__ bnshift,
    f16* __restrict__ y16) {
    __shared__ __align__(16) char smem[131072];
    int img = blockIdx.x / NSPB, sb = blockIdx.x % NSPB;
    int n0 = sb * SPT;
    int h_lo = n0 / GDIM;
    int half = blockIdx.y;
    int co0 = half * 256;
    int tid = threadIdx.x;
    int lane = tid & 63, wave = tid >> 6;
    int wm = wave >> 1, wn = wave & 1;
    int l15 = lane & 15, kg = lane >> 4;

    int roff[6];   // pixel offset * 8 (f16 units) in slab slot
#pragma unroll
    for (int nf = 0; nf < 6; ++nf) {
        int n = n0 + wn * 96 + nf * 16 + l15;
        int nc = n < GG ? n : GG - 1;
        int hh = nc / GDIM, ww = nc % GDIM;
        roff[nf] = ((hh - h_lo + 1) * PW + (ww + 1)) * 8;
    }

    f32x4 acc[4][6];
#pragma unroll
    for (int a = 0; a < 4; ++a)
#pragma unroll
        for (int b = 0; b < 6; ++b) {
            acc[a][b][0] = 0.f; acc[a][b][1] = 0.f;
            acc[a][b][2] = 0.f; acc[a][b][3] = 0.f;
        }

    const f16* xbase = x16p + ((size_t)img * 8 * PH + h_lo) * (PW * 32);
    f16x8 fa[2][4], fb[2][6];

    // ---- prologue: issue A(0), slab(0), A(1); vmcnt(2); barrier; read frags(0) ----
    {
        const f16* wA0 = w16 + (size_t)co0 * 32;                       // tap0 ck0
        f16* d0 = (f16*)(smem + AT_OFF);
#pragma unroll
        for (int p = 0; p < 2; ++p) {
            int u = p * 512 + tid, s = u >> 8, c = u & 255;
            gload16(wA0 + (size_t)c * 32 + s * 8, d0 + (size_t)u * 8);
        }
        f16* sd = (f16*)(smem + SLAB_OFF);
#pragma unroll
        for (int p = 0; p < 4; ++p) {
            int cix = p * 512 + tid;
            int pix = cix & 511; if (pix > 377) pix = 377;
            gload16(xbase + (size_t)pix * 32 + (cix >> 9) * 8, sd + (size_t)cix * 8);
        }
        const f16* wA1 = w16 + ((size_t)8 * 512 + co0) * 32;           // tap1 ck0
        f16* d1 = (f16*)(smem + AT_OFF + AT_SZ);
#pragma unroll
        for (int p = 0; p < 2; ++p) {
            int u = p * 512 + tid, s = u >> 8, c = u & 255;
            gload16(wA1 + (size_t)c * 32 + s * 8, d1 + (size_t)u * 8);
        }
    }
    VMCNT(2);
    __builtin_amdgcn_s_barrier();
    __builtin_amdgcn_sched_barrier(0);
    {   // frags(0): tap0, At[0], slab buf0
        const f16* Ab = (const f16*)(smem + AT_OFF);
        const f16* Sb = (const f16*)(smem + SLAB_OFF);
        const int tappix = -PW - 1;
#pragma unroll
        for (int mf = 0; mf < 4; ++mf)
            fa[0][mf] = *(const f16x8*)(Ab + kg * 2048 + (wm * 64 + l15) * 8 + mf * 128);
#pragma unroll
        for (int nf = 0; nf < 6; ++nf)
            fb[0][nf] = *(const f16x8*)(Sb + kg * 4096 + roff[nf] + tappix * 8);
    }
    __builtin_amdgcn_sched_barrier(0);

    for (int q = 0; q < 2; ++q) {
#pragma unroll
        for (int u = 0; u < 36; ++u) {     // t = q*36 + u; tap = u%9; ck = q*4+u/9
            // ---- slab stage (S first, then A) at u%9==1 ----
            if (u == 1 || u == 10 || u == 19 || u == 28) {
                int ckS = q * 4 + u / 9 + 1;
                const f16* sg;
                f16* sd;
                if (ckS > 7) {   // only q=1,u=28: dummy -> dead A-buf region
                    sg = xbase + (size_t)7 * (PH * PW * 32);
                    sd = (f16*)(smem + AT_OFF + ((u + 2) % 4) * AT_SZ);
                } else {
                    sg = xbase + (size_t)ckS * (PH * PW * 32);
                    sd = (f16*)(smem + SLAB_OFF + (((u / 9) + 1) & 1) * SLAB_SZ);
                }
#pragma unroll
                for (int p = 0; p < 4; ++p) {
                    int cix = p * 512 + tid;
                    int pix = cix & 511; if (pix > 377) pix = 377;
                    gload16(sg + (size_t)pix * 32 + (cix >> 9) * 8, sd + (size_t)cix * 8);
                }
            }
            // ---- A(t+2) DMA into At[(u+2)%4] ----
            {
                const int tap2 = (u + 2) % 9;
                int ckA = q * 4 + (u + 2) / 9; if (ckA > 7) ckA = 7;
                const f16* wA = w16 + ((size_t)(tap2 * 8 + ckA) * 512 + co0) * 32;
                f16* dst = (f16*)(smem + AT_OFF + ((u + 2) % 4) * AT_SZ);
#pragma unroll
                for (int p = 0; p < 2; ++p) {
                    int uu = p * 512 + tid, s = uu >> 8, c = uu & 255;
                    gload16(wA + (size_t)c * 32 + s * 8, dst + (size_t)uu * 8);
                }
            }
            // ---- counted wait + rendezvous ----
            if (u == 1 || u == 10 || u == 19 || u == 28) VMCNT(6); else VMCNT(2);
            __builtin_amdgcn_s_barrier();
            __builtin_amdgcn_sched_barrier(0);
            // ---- ds_read frags(t+1) into the alternate set ----
            {
                const int un = u + 1;
                const f16* Ab = (const f16*)(smem + AT_OFF + (un % 4) * AT_SZ);
                const f16* Sb = (const f16*)(smem + SLAB_OFF + ((un / 9) & 1) * SLAB_SZ);
                const int tapn = un % 9;
                const int tappix = (tapn / 3 - 1) * PW + (tapn % 3 - 1);
#pragma unroll
                for (int mf = 0; mf < 4; ++mf)
                    fa[un & 1][mf] = *(const f16x8*)(Ab + kg * 2048 +
                                                    (wm * 64 + l15) * 8 + mf * 128);
#pragma unroll
                for (int nf = 0; nf < 6; ++nf)
                    fb[un & 1][nf] = *(const f16x8*)(Sb + kg * 4096 +
                                                    roff[nf] + tappix * 8);
            }
            __builtin_amdgcn_sched_barrier(0);
            // ---- MFMA(t) from the current set ----
            __builtin_amdgcn_s_setprio(1);
#pragma unroll
            for (int nf = 0; nf < 6; ++nf)
#pragma unroll
                for (int mf = 0; mf < 4; ++mf)
                    acc[mf][nf] = __builtin_amdgcn_mfma_f32_16x16x32_f16(
                        fa[u & 1][mf], fb[u & 1][nf], acc[mf][nf], 0, 0, 0);
            __builtin_amdgcn_s_setprio(0);
            __builtin_amdgcn_sched_barrier(0);
        }
    }
    // ---- epilogue: BN + leaky -> LDS transpose (stride 264 f16) -> linear y16 ----
    __syncthreads();
    f16* tb = (f16*)smem;
#pragma unroll
    for (int mf = 0; mf < 4; ++mf) {
        int cr = wm * 64 + mf * 16 + kg * 4;
        f32x4 sc = *(const f32x4*)(bnscale + co0 + cr);
        f32x4 sh = *(const f32x4*)(bnshift + co0 + cr);
#pragma unroll
        for (int nf = 0; nf < 6; ++nf) {
            int pl = wn * 96 + nf * 16 + l15;
            f16x4 o;
#pragma unroll
            for (int i = 0; i < 4; ++i) {
                float v = acc[mf][nf][i] * sc[i] + sh[i];
                o[i] = (f16)(v > 0.f ? v : 0.1f * v);
            }
            *(f16x4*)(tb + pl * 264 + cr) = o;
        }
    }
    __syncthreads();
    int valid = GG - n0; if (valid > SPT) valid = SPT;
    f16* yb = y16 + (size_t)half * (NIMG * (size_t)GG * 256) + ((size_t)img * GG + n0) * 256;
#pragma unroll
    for (int p = 0; p < 12; ++p) {
        int u = p * 512 + tid, pl = u >> 5, slot = u & 31;
        if (pl < valid)
            *(f16x8*)(yb + (size_t)pl * 256 + slot * 8) =
                *(const f16x8*)(tb + pl * 264 + slot * 8);
    }
}

// ---- conv2 (1x1, K=512) + bias + YOLO decode. 256 thr / 4 waves, 128 n per block ----
__global__ __launch_bounds__(256) void k_conv2(
    const f16* __restrict__ y16, const f16* __restrict__ w2_16,
    const float* __restrict__ b2, float* __restrict__ out) {
    __shared__ float ct[128][81];   // 41472 B
    int img = blockIdx.x / 22, nb = blockIdx.x % 22;
    int n0 = nb * 128;
    int tid = threadIdx.x;
    int lane = tid & 63, wave = tid >> 6;
    int l15 = lane & 15, kg = lane >> 4;

    f32x4 acc[5][2];
#pragma unroll
    for (int a = 0; a < 5; ++a)
#pragma unroll
        for (int b = 0; b < 2; ++b) {
            acc[a][b][0] = 0.f; acc[a][b][1] = 0.f;
            acc[a][b][2] = 0.f; acc[a][b][3] = 0.f;
        }

    int nn[2];
#pragma unroll
    for (int nf = 0; nf < 2; ++nf) {
        int n = n0 + wave * 32 + nf * 16 + l15;
        nn[nf] = n < GG ? n : GG - 1;
    }
    for (int c0 = 0; c0 < CMID; c0 += 32) {
        const f16* yb = y16 + (size_t)(c0 >> 8) * (NIMG * (size_t)GG * 256) +
                        (size_t)img * GG * 256;
        int c = c0 & 255;
        f16x8 af[5];
#pragma unroll
        for (int mf = 0; mf < 5; ++mf) {
            int co = mf * 16 + l15;
            if (co < COUT)
                af[mf] = *(const f16x8*)(w2_16 + (size_t)co * CMID + c0 + kg * 8);
            else {
#pragma unroll
                for (int k = 0; k < 8; ++k) af[mf][k] = (f16)0;
            }
        }
#pragma unroll
        for (int nf = 0; nf < 2; ++nf) {
            f16x8 bf = *(const f16x8*)(yb + (size_t)nn[nf] * 256 + c + kg * 8);
#pragma unroll
            for (int mf = 0; mf < 5; ++mf)
                acc[mf][nf] = __builtin_amdgcn_mfma_f32_16x16x32_f16(
                    af[mf], bf, acc[mf][nf], 0, 0, 0);
        }
    }
#pragma unroll
    for (int mf = 0; mf < 5; ++mf)
#pragma unroll
        for (int nf = 0; nf < 2; ++nf)
            *(f32x4*)(&ct[wave * 32 + nf * 16 + l15][mf * 16 + kg * 4]) = acc[mf][nf];
    __syncthreads();
    // decode: 384 (anchor, n) items over 256 threads
    for (int j = tid; j < 384; j += 256) {
        int a = j >> 7, nl = j & 127;
        int n = n0 + nl;
        if (n >= GG) continue;
        const float* t = &ct[nl][a * 25];
        float tv[25];
#pragma unroll
        for (int q = 0; q < 25; ++q) tv[q] = t[q] + b2[a * 25 + q];
        int h = n / GDIM, w = n % GDIM;
        const float AW[3] = {10.f, 16.f, 33.f};
        const float AH[3] = {13.f, 30.f, 23.f};
        float bx = (sigmoidf_(tv[0]) + (float)w) * 8.0f;
        float by = (sigmoidf_(tv[1]) + (float)h) * 8.0f;
        float bw_ = __expf(tv[2]) * AW[a];
        float bh_ = __expf(tv[3]) * AH[a];
        float* o = out + ((size_t)img * 8112 + (size_t)a * GG + n) * 25;
        o[0] = bx; o[1] = by; o[2] = bw_; o[3] = bh_;
        o[4] = sigmoidf_(tv[4]);
#pragma unroll
        for (int q = 0; q < 20; ++q) o[5 + q] = sigmoidf_(tv[5 + q]);
    }
}

extern "C" void kernel_launch(void* const* d_in, const int* in_sizes, int n_in,
                              void* d_out, int out_size, void* d_ws, size_t ws_size,
                              hipStream_t stream) {
    (void)in_sizes; (void)n_in; (void)out_size; (void)ws_size;
    const float* x     = (const float*)d_in[0];
    const float* w1    = (const float*)d_in[1];
    const float* gamma = (const float*)d_in[2];
    const float* beta  = (const float*)d_in[3];
    const float* mean  = (const float*)d_in[4];
    const float* var   = (const float*)d_in[5];
    const float* w2    = (const float*)d_in[6];
    const float* b2    = (const float*)d_in[7];
    float* out = (float*)d_out;

    char* ws = (char*)d_ws;
    // x16p: 16*8*60*54*32*2 = 26,542,080 B
    f16* x16p     = (f16*)(ws);
    f16* w16      = (f16*)(ws + 26542080);     // 2,359,296 B
    f16* w2_16    = (f16*)(ws + 28901376);     //    76,800 B
    float* bnscale = (float*)(ws + 28978176);  //     2,048 B
    float* bnshift = (float*)(ws + 28980224);  //     2,048 B
    f16* y16      = (f16*)(ws + 28982272);     // 44,302,336 B (total ~73.3 MB)

    k_zero_border<<<NIMG * 8, 256, 0, stream>>>(x16p);
    k_prep_x<<<dim3(22, 8, NIMG), 256, 0, stream>>>(x, x16p);
    k_prep_w<<<4608, 256, 0, stream>>>(w1, w2, gamma, beta, mean, var,
                                       w16, w2_16, bnscale, bnshift);
    k_conv1<<<dim3(NIMG * NSPB, 2), 512, 0, stream>>>(x16p, w16, bnscale,
                                                      bnshift, y16);
    k_conv2<<<NIMG * 22, 256, 0, stream>>>(y16, w2_16, b2, out);
}